// Round 16
// baseline (208.746 us; speedup 1.0000x reference)
//
#include <hip/hip_runtime.h>
#include <hip/hip_bf16.h>
#include <stdint.h>

// Router GEMM: out[8192,768] (fp32) = X[8192,6144] @ W[768,6144]^T
// Device buffers hold FP32 upcasts of the bf16 data (round-6 discovery).
// Round 16: ATTACK THE MEASURED ~10.3 TB/s BEYOND-L2 CEILING (r6/r8/r11/r12/
// r15 all pinned there). Reduce bytes, not schedule:
//   1) bf16 pre-pass into d_ws (halves all fabric crossings; ~330MB HBM once)
//   2) BM=256 (B-side far-traffic halves), BN=128, BK=32, SK=4
//   3) bn-fastest in-XCD order: 6 bn-sharers of each 786KB X quarter-panel
//      run in phase -> X crosses fabric ~once; ks outer keeps W slice L2-hot
//   4) r15's 1-barrier dbuf schedule; bf16 staging regs (6 vs 64) -> fits
//      2 blocks/CU at (512,4) with acc=64 (budget ~120 <= 128, checked)
// Fallback: ws too small -> r8 champion verbatim (161us known-good).

#define M_DIM 8192
#define N_DIM 768
#define K_DIM 6144

#define BM 256
#define BN 128
#define BK 32
#define SPLITK 4
#define KSEG (K_DIM / SPLITK)    // 1536
#define NT (KSEG / BK)           // 48 (even)

#define NX_ELEM ((size_t)M_DIM * K_DIM)          // 50331648
#define NW_ELEM ((size_t)N_DIM * K_DIM)          // 4718592
#define WS_NEED ((NX_ELEM + NW_ELEM) * 2)        // 110100480 bytes

typedef __bf16 bf16x8 __attribute__((ext_vector_type(8)));
typedef float f32x4 __attribute__((ext_vector_type(4)));

static __device__ __forceinline__ __bf16 bf16_trunc(float f) {
    uint32_t u = __builtin_bit_cast(uint32_t, f);
    return __builtin_bit_cast(__bf16, (uint16_t)(u >> 16));  // exact on upcast data
}

static __device__ __forceinline__ bf16x8 pack_bf16x8(f32x4 a, f32x4 b) {
    bf16x8 r;
    #pragma unroll
    for (int j = 0; j < 4; ++j) {
        r[j]     = bf16_trunc(a[j]);
        r[4 + j] = bf16_trunc(b[j]);
    }
    return r;
}

// ---------------- pre-pass: fp32 -> bf16 (X then W), fully coalesced --------
__global__ __launch_bounds__(256) void convert_bf16_kernel(
    const float* __restrict__ X, const float* __restrict__ W,
    __bf16* __restrict__ Xb, __bf16* __restrict__ Wb)
{
    const size_t NXU = NX_ELEM / 8;
    const size_t NTU = (NX_ELEM + NW_ELEM) / 8;
    for (size_t u = (size_t)blockIdx.x * 256 + threadIdx.x; u < NTU;
         u += (size_t)gridDim.x * 256) {
        const float* s;
        __bf16* d;
        if (u < NXU) { s = X + u * 8;          d = Xb + u * 8; }
        else         { s = W + (u - NXU) * 8;  d = Wb + (u - NXU) * 8; }
        f32x4 lo = *(const f32x4*)s;
        f32x4 hi = *(const f32x4*)(s + 4);
        *(bf16x8*)d = pack_bf16x8(lo, hi);
    }
}

// ---------------- main GEMM: bf16 inputs, BM=256 ----------------------------
__global__ __launch_bounds__(512, 4) void router_gemm_bf16_kernel(
    const __bf16* __restrict__ X, const __bf16* __restrict__ W,
    float* __restrict__ out)
{
    // double-buffered tiles [buf][row][32 k] bf16: A 2x16KB + B 2x8KB = 48KB
    __shared__ __align__(16) __bf16 As[2][BM * BK];
    __shared__ __align__(16) __bf16 Bs[2][BN * BK];

    const int tid  = threadIdx.x;
    const int w    = tid >> 6;             // wave 0..7
    const int lane = tid & 63;

    // block decode: xcd round-robin; within XCD: bn FASTEST (X-panel sharers
    // in phase), bmi mid, ks OUTER (W ks-slice stays L2-resident).
    const int xcd  = blockIdx.x & 7;
    const int slot = blockIdx.x >> 3;      // 0..95
    const int bn   = slot % 6;             // 0..5
    const int bmi  = (slot / 6) & 3;       // 0..3
    const int ks   = slot / 24;            // 0..3
    const int bm   = xcd * 4 + bmi;        // 0..31

    const int kbase = ks * KSEG;

    const int wr = w >> 1;                 // wave row 0..3 (64 m each)
    const int wc = w & 1;                  // wave col 0..1 (64 n each)

    const int lrow = lane & 15;
    const int kg   = lane >> 4;

    // staging: 3 units/thread (A rows srow, srow+128; B row srow)
    const int srow = tid >> 2;             // 0..127
    const int k8   = tid & 3;              // k-unit 0..3
    // r9-verified conflict-free swizzle: slot = k8 ^ ((row>>1)&3)
    // ((srow+128)>>1)&3 == (srow>>1)&3, so one wslot serves both A rows.
    const int wslot = (k8 ^ ((srow >> 1) & 3)) * 8;

    const __bf16* xa0 = X + (size_t)(bm * BM + srow) * K_DIM + k8 * 8;
    const __bf16* xa1 = xa0 + (size_t)128 * K_DIM;
    const __bf16* wb0 = W + (size_t)(bn * BN + srow) * K_DIM + k8 * 8;

    bf16x8 pr[3];

    #define ISSUE(K0)                                   \
        do {                                            \
            pr[0] = *(const bf16x8*)(xa0 + (K0));       \
            pr[1] = *(const bf16x8*)(xa1 + (K0));       \
            pr[2] = *(const bf16x8*)(wb0 + (K0));       \
        } while (0)

    #define WRITE_LDS(BUF)                                              \
        do {                                                            \
            *(bf16x8*)(As[BUF] + srow * BK + wslot)         = pr[0];    \
            *(bf16x8*)(As[BUF] + (srow + 128) * BK + wslot) = pr[1];    \
            *(bf16x8*)(Bs[BUF] + srow * BK + wslot)         = pr[2];    \
        } while (0)

    f32x4 acc[4][4] = {};

    const int rslot = (kg ^ ((lrow >> 1) & 3)) * 8;
    const int arow0 = wr * 64 + lrow;      // + mf*16  (max 255)
    const int brow0 = wc * 64 + lrow;      // + nf*16  (max 127)

    #define COMPUTE(BUF)                                                      \
        do {                                                                  \
            bf16x8 a[4], b[4];                                                \
            _Pragma("unroll")                                                 \
            for (int mf = 0; mf < 4; ++mf)                                    \
                a[mf] = *(const bf16x8*)(As[BUF]                              \
                            + (arow0 + mf * 16) * BK + rslot);                \
            _Pragma("unroll")                                                 \
            for (int nf = 0; nf < 4; ++nf)                                    \
                b[nf] = *(const bf16x8*)(Bs[BUF]                              \
                            + (brow0 + nf * 16) * BK + rslot);                \
            _Pragma("unroll")                                                 \
            for (int mf = 0; mf < 4; ++mf)                                    \
                _Pragma("unroll")                                             \
                for (int nf = 0; nf < 4; ++nf)                                \
                    acc[mf][nf] = __builtin_amdgcn_mfma_f32_16x16x32_bf16(    \
                        a[mf], b[nf], acc[mf][nf], 0, 0, 0);                  \
        } while (0)

    // prologue
    ISSUE(kbase);
    WRITE_LDS(0);
    __syncthreads();

    for (int t = 0; t < NT; t += 2) {
        if (t + 1 < NT) ISSUE(kbase + (t + 1) * BK);
        COMPUTE(0);
        if (t + 1 < NT) WRITE_LDS(1);   // buf1 readers finished before prev bar
        __syncthreads();
        if (t + 2 < NT) ISSUE(kbase + (t + 2) * BK);
        COMPUTE(1);
        if (t + 2 < NT) WRITE_LDS(0);   // buf0 readers finished before mid bar
        __syncthreads();
    }

    // epilogue: relaxed device-scope fp32 atomic add (out zeroed in launch).
    // C/D layout: col = lane&15, row = (lane>>4)*4 + reg (verified).
    const int orow0 = bm * BM + wr * 64 + kg * 4;
    const int ocol0 = bn * BN + wc * 64 + lrow;
    #pragma unroll
    for (int mf = 0; mf < 4; ++mf)
        #pragma unroll
        for (int nf = 0; nf < 4; ++nf)
            #pragma unroll
            for (int r = 0; r < 4; ++r) {
                float* o = out + (size_t)(orow0 + mf * 16 + r) * N_DIM
                               + (ocol0 + nf * 16);
                __hip_atomic_fetch_add(o, acc[mf][nf][r],
                                       __ATOMIC_RELAXED, __HIP_MEMORY_SCOPE_AGENT);
            }

    #undef ISSUE
    #undef WRITE_LDS
    #undef COMPUTE
}

// ---------------- fallback: r8 champion verbatim (fp32 inputs) --------------
__global__ __launch_bounds__(256, 3) void router_gemm_fb_kernel(
    const float* __restrict__ X, const float* __restrict__ W,
    float* __restrict__ out)
{
    __shared__ __align__(16) __bf16 Af[128 * 32];
    __shared__ __align__(16) __bf16 Bf[128 * 32];

    const int tid  = threadIdx.x;
    const int w    = tid >> 6;
    const int lane = tid & 63;

    const int xcd  = blockIdx.x & 7;
    const int slot = blockIdx.x >> 3;
    const int bmi  = slot & 7;
    const int tt   = slot >> 3;
    const int bn   = tt % 6;
    const int ks   = tt / 6;
    const int bm   = xcd * 8 + bmi;

    const int kbase = ks * 3072;
    const int wr = w >> 1, wc = w & 1;
    const int lrow = lane & 15, kg = lane >> 4;
    const int srow = tid >> 2, sk8 = tid & 3;
    const int wslot0 = (sk8 ^ ((srow >> 1) & 3)) * 8;

    const float* Xg = X + (size_t)(bm * 128) * K_DIM;
    const float* Wg = W + (size_t)(bn * 128) * K_DIM;
    const float* xrow0 = Xg + (size_t)srow * K_DIM + sk8 * 8;
    const float* xrow1 = xrow0 + (size_t)64 * K_DIM;
    const float* wrow0 = Wg + (size_t)srow * K_DIM + sk8 * 8;
    const float* wrow1 = wrow0 + (size_t)64 * K_DIM;

    f32x4 pr[8];
    f32x4 acc[4][4] = {};
    const int rslot = (kg ^ ((lrow >> 1) & 3)) * 8;
    const int arow0 = wr * 64 + lrow;
    const int brow0 = wc * 64 + lrow;

    for (int t = 0; t < 96; ++t) {
        const int k0 = kbase + t * 32;
        pr[0] = *(const f32x4*)(xrow0 + k0);
        pr[1] = *(const f32x4*)(xrow0 + k0 + 4);
        pr[2] = *(const f32x4*)(xrow1 + k0);
        pr[3] = *(const f32x4*)(xrow1 + k0 + 4);
        pr[4] = *(const f32x4*)(wrow0 + k0);
        pr[5] = *(const f32x4*)(wrow0 + k0 + 4);
        pr[6] = *(const f32x4*)(wrow1 + k0);
        pr[7] = *(const f32x4*)(wrow1 + k0 + 4);
        __syncthreads();
        *(bf16x8*)(Af + srow * 32 + wslot0)        = pack_bf16x8(pr[0], pr[1]);
        *(bf16x8*)(Af + (srow + 64) * 32 + wslot0) = pack_bf16x8(pr[2], pr[3]);
        *(bf16x8*)(Bf + srow * 32 + wslot0)        = pack_bf16x8(pr[4], pr[5]);
        *(bf16x8*)(Bf + (srow + 64) * 32 + wslot0) = pack_bf16x8(pr[6], pr[7]);
        __syncthreads();
        bf16x8 a[4], b[4];
        #pragma unroll
        for (int mf = 0; mf < 4; ++mf)
            a[mf] = *(const bf16x8*)(Af + (arow0 + mf * 16) * 32 + rslot);
        #pragma unroll
        for (int nf = 0; nf < 4; ++nf)
            b[nf] = *(const bf16x8*)(Bf + (brow0 + nf * 16) * 32 + rslot);
        #pragma unroll
        for (int mf = 0; mf < 4; ++mf)
            #pragma unroll
            for (int nf = 0; nf < 4; ++nf)
                acc[mf][nf] = __builtin_amdgcn_mfma_f32_16x16x32_bf16(
                    a[mf], b[nf], acc[mf][nf], 0, 0, 0);
    }

    const int orow0 = bm * 128 + wr * 64 + kg * 4;
    const int ocol0 = bn * 128 + wc * 64 + lrow;
    #pragma unroll
    for (int mf = 0; mf < 4; ++mf)
        #pragma unroll
        for (int nf = 0; nf < 4; ++nf)
            #pragma unroll
            for (int r = 0; r < 4; ++r) {
                float* o = out + (size_t)(orow0 + mf * 16 + r) * N_DIM
                               + (ocol0 + nf * 16);
                __hip_atomic_fetch_add(o, acc[mf][nf][r],
                                       __ATOMIC_RELAXED, __HIP_MEMORY_SCOPE_AGENT);
            }
}

extern "C" void kernel_launch(void* const* d_in, const int* in_sizes, int n_in,
                              void* d_out, int out_size, void* d_ws, size_t ws_size,
                              hipStream_t stream) {
    const float* X;
    const float* W;
    if (in_sizes[0] == (int)(M_DIM * (size_t)K_DIM)) {
        X = (const float*)d_in[0];
        W = (const float*)d_in[1];
    } else {
        X = (const float*)d_in[1];
        W = (const float*)d_in[0];
    }
    float* out = (float*)d_out;

    hipMemsetAsync(out, 0, (size_t)M_DIM * N_DIM * sizeof(float), stream);

    if (ws_size >= WS_NEED) {
        __bf16* Xb = (__bf16*)d_ws;
        __bf16* Wb = Xb + NX_ELEM;
        hipLaunchKernelGGL(convert_bf16_kernel, dim3(2048), dim3(256), 0, stream,
                           X, W, Xb, Wb);
        const int grid = 8 * 96;   // 32 bm x 6 bn x 4 ks = 768, 2/CU resident
        hipLaunchKernelGGL(router_gemm_bf16_kernel, dim3(grid), dim3(512), 0,
                           stream, Xb, Wb, out);
    } else {
        const int grid = 8 * 96;   // r8 champion path
        hipLaunchKernelGGL(router_gemm_fb_kernel, dim3(grid), dim3(256), 0,
                           stream, X, W, out);
    }
}